// Round 7
// baseline (1646.137 us; speedup 1.0000x reference)
//
#include <hip/hip_runtime.h>
#include <hip/hip_cooperative_groups.h>
#include <hip/hip_bf16.h>
#include <cstddef>

namespace cg = cooperative_groups;

#define DD 512
#define DKK 64
#define SS 64
#define BS 2048
#define FF 2048
#define VV 8000
#define LL 4
#define BN_SCALE 0.9995003746f
#define FG_KS 8
#define FG_KCH 4096

// attn LDS layout (each [64][72] bf16 = 9216 B); Ws aliases QB..VT region
#define QB_OFF 0
#define KB_OFF 9216
#define VT_OFF 18432
#define PB_OFF 27648
#define HB_OFF 36864
#define ATTN_SMEM 46080
#define MEGA_SMEM 49152

typedef __attribute__((ext_vector_type(8))) short short8;
typedef __attribute__((ext_vector_type(4))) float f32x4;
typedef __hip_bfloat16 bf16;

__device__ __forceinline__ void gload16(const void* g, void* l) {
  __builtin_amdgcn_global_load_lds((const __attribute__((address_space(1))) void*)g,
                                   (__attribute__((address_space(3))) void*)l, 16, 0, 0);
}
__device__ __forceinline__ bf16 tob(float v) { return __float2bfloat16(v); }

struct Params {
  const int* seq; const float* enc; const float* pes; const float* emb;
  const float* sa_wq; const float* sa_bq; const float* sa_wk; const float* sa_bk;
  const float* sa_wv; const float* sa_bv; const float* sa_wo; const float* sa_bo;
  const float* ca_wq; const float* ca_bq; const float* ca_wk; const float* ca_bk;
  const float* ca_wv; const float* ca_bv; const float* ca_wo; const float* ca_bo;
  const float* f_w1; const float* f_b1; const float* f_w2; const float* f_b2;
  const float* bn_g; const float* bn_b; const float* out_w; const float* out_b;
  float* out;
  float* x0; float* x1;
  bf16 *xb0, *xb1, *h, *w1T, *w2T, *qkvTs, *qkvTc, *woTs, *woTc, *encb, *kca, *vtca;
  float* fpart;
};

// ================= phase: preprocessing =================
__device__ void phase_prep(const Params& p, char* smem) {
  float (*t)[33] = (float(*)[33])smem;
  const int tid = threadIdx.x, tx = tid & 31, ty = tid >> 5;
  for (int u = blockIdx.x; u < 17408; u += gridDim.x) {
    const float* src = nullptr; bf16* dst = nullptr;
    int srcld = 0, dstld = 0, n0 = 0, k0 = 0;
    bool istr = true;
    if (u < 4096) {                     // w1: [L][512][2048] -> [L][2048][512]
      int z = u >> 10, rem = u & 1023, kb = rem >> 6, nb = rem & 63;
      src = p.f_w1 + (size_t)z * DD * FF; srcld = FF;
      dst = p.w1T + (size_t)z * FF * DD; dstld = DD; n0 = nb * 32; k0 = kb * 32;
    } else if (u < 8192) {              // w2: [L][2048][512] -> [L][512][2048]
      int q = u - 4096, z = q >> 10, rem = q & 1023, nb = rem & 15, kb = rem >> 4;
      src = p.f_w2 + (size_t)z * FF * DD; srcld = DD;
      dst = p.w2T + (size_t)z * DD * FF; dstld = FF; n0 = nb * 32; k0 = kb * 32;
    } else if (u < 8960) {              // qkv: [512][64] -> rows of [192][512]
      int q = u - 8192, z = q >> 5, rem = q & 31, nb = rem & 1, kb = rem >> 1;
      int side = z / 12, r2 = z % 12, i = r2 / 3, wh = r2 % 3;
      int sel = side * 3 + wh;
      const float* base = sel == 0 ? p.sa_wq : sel == 1 ? p.sa_wk : sel == 2 ? p.sa_wv
                        : sel == 3 ? p.ca_wq : sel == 4 ? p.ca_wk : p.ca_wv;
      src = base + (size_t)i * DD * DKK; srcld = DKK;
      dst = (side ? p.qkvTc : p.qkvTs) + (size_t)i * 192 * DD + (size_t)wh * 64 * DD;
      dstld = DD; n0 = nb * 32; k0 = kb * 32;
    } else if (u < 9216) {              // wo: [64][512] -> [512][64]
      int q = u - 8960, z = q >> 5, rem = q & 31, nb = rem >> 1, kb = rem & 1;
      int side = z / LL, i = z % LL;
      src = (side ? p.ca_wo : p.sa_wo) + (size_t)i * DKK * DD; srcld = DD;
      dst = (side ? p.woTc : p.woTs) + (size_t)i * DD * DKK; dstld = DKK;
      n0 = nb * 32; k0 = kb * 32;
    } else if (u < 13312) {             // enc -> bf16
      istr = false;
      int i0 = (u - 9216) * 256 + tid;
      p.encb[i0] = tob(p.enc[i0]);
    } else {                            // embedding
      istr = false;
      int idx = (u - 13312) * 256 + tid;
      int bs = idx / DD, d = idx % DD, s = bs % SS;
      float v = p.emb[(size_t)p.seq[bs] * DD + d] + p.pes[s * DD + d];
      p.x0[idx] = v; p.xb0[idx] = tob(v);
    }
    if (istr) {
#pragma unroll
      for (int pp = 0; pp < 4; ++pp)
        t[ty + pp * 8][tx] = src[(size_t)(k0 + ty + pp * 8) * srcld + n0 + tx];
      __syncthreads();
#pragma unroll
      for (int pp = 0; pp < 4; ++pp)
        dst[(size_t)(n0 + ty + pp * 8) * dstld + k0 + tx] = tob(t[tx][ty + pp * 8]);
      __syncthreads();
    }
  }
}

// ================= phase: CA K/V precompute (all layers) =================
__device__ void phase_cakv(const Params& p, char* smem) {
  bf16 (*Ws)[72] = (bf16(*)[72])smem;   // 128 rows (Wk^T | Wv^T) = 18432 B
  const int tid = threadIdx.x, w = tid >> 6, lane = tid & 63;
  const int l15 = lane & 15, lhi = lane >> 4;
  for (int u = blockIdx.x; u < 128; u += gridDim.x) {
    const int b = u & 31, i = u >> 5;
    const bf16* wT = p.qkvTc + (size_t)i * 192 * DD + (size_t)64 * DD;
    f32x4 acc[8] = {};
    for (int kc = 0; kc < DD; kc += 64) {
      __syncthreads();
#pragma unroll
      for (int v = 0; v < 4; ++v) {
        int idx = v * 256 + tid, row = idx >> 3, c8 = idx & 7;
        *(short8*)&Ws[row][c8 * 8] = *(const short8*)(wT + (size_t)row * DD + kc + c8 * 8);
      }
      __syncthreads();
#pragma unroll
      for (int kk = 0; kk < 2; ++kk) {
        short8 ae = *(const short8*)(p.encb + (size_t)(b * 64 + w * 16 + l15) * DD + kc + kk * 32 + lhi * 8);
#pragma unroll
        for (int f = 0; f < 8; ++f) {
          short8 bfr = *(const short8*)&Ws[f * 16 + l15][kk * 32 + lhi * 8];
          acc[f] = __builtin_amdgcn_mfma_f32_16x16x32_bf16(ae, bfr, acc[f], 0, 0, 0);
        }
      }
    }
    const float* bk = p.ca_bk + i * DKK;
    const float* bv = p.ca_bv + i * DKK;
#pragma unroll
    for (int f = 0; f < 8; ++f) {
      int c = f * 16 + l15;
#pragma unroll
      for (int r = 0; r < 4; ++r) {
        int row = w * 16 + lhi * 4 + r;
        if (f < 4)
          p.kca[((size_t)i * BS + b * 64 + row) * DKK + c] = tob(acc[f][r] + bk[c]);
        else {
          int d = c - 64;
          p.vtca[(((size_t)i * 32 + b) * DKK + d) * 64 + row] = tob(acc[f][r] + bv[d]);
        }
      }
    }
    __syncthreads();
  }
}

// ================= phase: fused attention =================
template <bool CAUSAL>
__device__ void phase_attn(const Params& p, char* smem, int i, const bf16* qin,
                           const float* xres, float* xout, bf16* xbout) {
  bf16 (*Ws)[72] = (bf16(*)[72])smem;
  bf16 (*Qb)[72] = (bf16(*)[72])(smem + QB_OFF);
  bf16 (*Kb)[72] = (bf16(*)[72])(smem + KB_OFF);
  bf16 (*Vt)[72] = (bf16(*)[72])(smem + VT_OFF);
  bf16 (*Pb)[72] = (bf16(*)[72])(smem + PB_OFF);
  bf16 (*Hb)[72] = (bf16(*)[72])(smem + HB_OFF);
  const int tid = threadIdx.x, w = tid >> 6, lane = tid & 63;
  const int l15 = lane & 15, lhi = lane >> 4;

  const bf16* qkvT = (CAUSAL ? p.qkvTs : p.qkvTc) + (size_t)i * 192 * DD;
  const bf16* woT  = (CAUSAL ? p.woTs  : p.woTc ) + (size_t)i * DD * DKK;
  const float* bq = (CAUSAL ? p.sa_bq : p.ca_bq) + i * DKK;
  const float* bo = (CAUSAL ? p.sa_bo : p.ca_bo) + (size_t)i * DD;
  const float* gamma = p.bn_g + (size_t)(i * 3 + (CAUSAL ? 0 : 1)) * DD;
  const float* beta  = p.bn_b + (size_t)(i * 3 + (CAUSAL ? 0 : 1)) * DD;

  for (int u = blockIdx.x; u < 256; u += gridDim.x) {
    const int chunk = u >> 5, b = u & 31, col0 = chunk * 64;
    const size_t abase = (size_t)(b * SS) * DD;

    // ---- phase A: projections
    if (CAUSAL) {
      const float* bk = p.sa_bk + i * DKK;
      const float* bv = p.sa_bv + i * DKK;
      f32x4 acc[12] = {};
      for (int kc = 0; kc < DD; kc += 64) {
        __syncthreads();
#pragma unroll
        for (int v = 0; v < 6; ++v) {
          int idx = v * 256 + tid, row = idx >> 3, c8 = idx & 7;
          *(short8*)&Ws[row][c8 * 8] = *(const short8*)(qkvT + (size_t)row * DD + kc + c8 * 8);
        }
        __syncthreads();
#pragma unroll
        for (int kk = 0; kk < 2; ++kk) {
          short8 aq = *(const short8*)(qin + abase + (size_t)(w * 16 + l15) * DD + kc + kk * 32 + lhi * 8);
#pragma unroll
          for (int f = 0; f < 12; ++f) {
            short8 bfr = *(const short8*)&Ws[f * 16 + l15][kk * 32 + lhi * 8];
            acc[f] = __builtin_amdgcn_mfma_f32_16x16x32_bf16(aq, bfr, acc[f], 0, 0, 0);
          }
        }
      }
      __syncthreads();                  // Ws reads done before Q/K/V overwrite
#pragma unroll
      for (int f = 0; f < 12; ++f) {
        int c = (f & 3) * 16 + l15;
#pragma unroll
        for (int r = 0; r < 4; ++r) {
          int row = w * 16 + lhi * 4 + r;
          if (f < 4)      Qb[row][c] = tob((acc[f][r] + bq[c]) * 0.125f);
          else if (f < 8) Kb[row][c] = tob(acc[f][r] + bk[c]);
          else            Vt[c][row] = tob(acc[f][r] + bv[c]);
        }
      }
    } else {
      // stage precomputed K,V (disjoint from 64-row Ws region at offset 0)
#pragma unroll
      for (int v = 0; v < 2; ++v) {
        int idx = v * 256 + tid, r = idx >> 3, c8 = idx & 7;
        *(short8*)&Kb[r][c8 * 8] = *(const short8*)(p.kca + ((size_t)i * BS + b * 64 + r) * DKK + c8 * 8);
        *(short8*)&Vt[r][c8 * 8] = *(const short8*)(p.vtca + (((size_t)i * 32 + b) * DKK + r) * 64 + c8 * 8);
      }
      f32x4 acc[4] = {};
      for (int kc = 0; kc < DD; kc += 64) {
        __syncthreads();
#pragma unroll
        for (int v = 0; v < 2; ++v) {
          int idx = v * 256 + tid, row = idx >> 3, c8 = idx & 7;
          *(short8*)&Ws[row][c8 * 8] = *(const short8*)(qkvT + (size_t)row * DD + kc + c8 * 8);
        }
        __syncthreads();
#pragma unroll
        for (int kk = 0; kk < 2; ++kk) {
          short8 aq = *(const short8*)(qin + abase + (size_t)(w * 16 + l15) * DD + kc + kk * 32 + lhi * 8);
#pragma unroll
          for (int f = 0; f < 4; ++f) {
            short8 bfr = *(const short8*)&Ws[f * 16 + l15][kk * 32 + lhi * 8];
            acc[f] = __builtin_amdgcn_mfma_f32_16x16x32_bf16(aq, bfr, acc[f], 0, 0, 0);
          }
        }
      }
      __syncthreads();                  // Ws reads done before Qb overwrite
#pragma unroll
      for (int f = 0; f < 4; ++f) {
        int c = f * 16 + l15;
#pragma unroll
        for (int r = 0; r < 4; ++r)
          Qb[w * 16 + lhi * 4 + r][c] = tob((acc[f][r] + bq[c]) * 0.125f);
      }
    }
    __syncthreads();

    // ---- phase B: S = Q @ K^T + softmax
    f32x4 sacc[4] = {};
#pragma unroll
    for (int kk = 0; kk < 2; ++kk) {
      short8 aq = *(const short8*)&Qb[w * 16 + l15][kk * 32 + lhi * 8];
#pragma unroll
      for (int f = 0; f < 4; ++f) {
        short8 bfr = *(const short8*)&Kb[f * 16 + l15][kk * 32 + lhi * 8];
        sacc[f] = __builtin_amdgcn_mfma_f32_16x16x32_bf16(aq, bfr, sacc[f], 0, 0, 0);
      }
    }
#pragma unroll
    for (int r = 0; r < 4; ++r) {
      int qr = w * 16 + lhi * 4 + r;
      float sv[4], m = -3.0e38f;
#pragma unroll
      for (int f = 0; f < 4; ++f) {
        int kt = f * 16 + l15;
        bool valid = (!CAUSAL) || (kt < qr);
        sv[f] = valid ? sacc[f][r] : -3.0e38f;
        m = fmaxf(m, sv[f]);
      }
#pragma unroll
      for (int off = 1; off < 16; off <<= 1) m = fmaxf(m, __shfl_xor(m, off));
      float pv[4], sum = 0.f;
#pragma unroll
      for (int f = 0; f < 4; ++f) {
        pv[f] = (sv[f] > -1.0e38f) ? __expf(sv[f] - m) : 0.f;
        sum += pv[f];
      }
#pragma unroll
      for (int off = 1; off < 16; off <<= 1) sum += __shfl_xor(sum, off);
      float rs = sum > 0.f ? 1.f / sum : 0.f;
#pragma unroll
      for (int f = 0; f < 4; ++f)
        Pb[qr][f * 16 + l15] = tob(pv[f] * rs);
    }
    __syncthreads();

    // ---- phase C: head = P @ V
    f32x4 hacc[4] = {};
#pragma unroll
    for (int kk = 0; kk < 2; ++kk) {
      short8 ap = *(const short8*)&Pb[w * 16 + l15][kk * 32 + lhi * 8];
#pragma unroll
      for (int f = 0; f < 4; ++f) {
        short8 bfr = *(const short8*)&Vt[f * 16 + l15][kk * 32 + lhi * 8];
        hacc[f] = __builtin_amdgcn_mfma_f32_16x16x32_bf16(ap, bfr, hacc[f], 0, 0, 0);
      }
    }
#pragma unroll
    for (int f = 0; f < 4; ++f)
#pragma unroll
      for (int r = 0; r < 4; ++r)
        Hb[w * 16 + lhi * 4 + r][f * 16 + l15] = tob(hacc[f][r]);
    __syncthreads();

    // ---- phase D: out = head @ Wo (64-col chunk) + bo, +residual, BN
    f32x4 oacc[4] = {};
#pragma unroll
    for (int kk = 0; kk < 2; ++kk) {
      short8 ah = *(const short8*)&Hb[w * 16 + l15][kk * 32 + lhi * 8];
#pragma unroll
      for (int f = 0; f < 4; ++f) {
        short8 bfr = *(const short8*)(woT + (size_t)(col0 + f * 16 + l15) * DKK + kk * 32 + lhi * 8);
        oacc[f] = __builtin_amdgcn_mfma_f32_16x16x32_bf16(ah, bfr, oacc[f], 0, 0, 0);
      }
    }
#pragma unroll
    for (int f = 0; f < 4; ++f) {
      int c = col0 + f * 16 + l15;
      float g = gamma[c], be = beta[c], bb = bo[c];
#pragma unroll
      for (int r = 0; r < 4; ++r) {
        int row = b * SS + w * 16 + lhi * 4 + r;
        float v = oacc[f][r] + bb;
        float res = xres[(size_t)row * DD + c] + v;
        float y = g * (res * BN_SCALE) + be;
        xout[(size_t)row * DD + c]  = y;
        xbout[(size_t)row * DD + c] = tob(y);
      }
    }
    __syncthreads();
  }
}

// ================= phase: bf16 MFMA GEMM (tile loop) =================
template <int BM, int BN, int WM, int WN, int EPI>
__device__ void phase_mm(char* smem, const bf16* A, const bf16* BT, int K, int N,
                         const float* bias, bf16* outb, float* outf,
                         const float* xres, const float* gamma, const float* beta,
                         int MT, int NT) {
  constexpr int NA = BM * 64 / 8 / 256;
  constexpr int NB = BN * 64 / 8 / 256;
  constexpr int FM = BM / (WM * 16), FN = BN / (WN * 16);
  bf16* As = (bf16*)smem;                       // [2][BM*64]
  bf16* Bs = (bf16*)smem + 2 * BM * 64;         // [2][BN*64]
  const int tid = threadIdx.x, lane = tid & 63, w = tid >> 6;
  const int wr = w / WN, wc = w % WN;
  const int l15 = lane & 15, lhi = lane >> 4;

  for (int t0 = blockIdx.x; t0 < MT * NT; t0 += gridDim.x) {
    const int row0 = (t0 % MT) * BM, col0 = (t0 / MT) * BN;
    f32x4 acc[FM][FN] = {};

    auto stage = [&](int buf, int kc) {
#pragma unroll
      for (int c = 0; c < NA; ++c) {
        int j = c * 256 + tid, r = j >> 3, c8 = j & 7;
        gload16(A + (size_t)(row0 + r) * K + kc + c8 * 8, As + (size_t)buf * BM * 64 + (c * 256 + w * 64) * 8);
      }
#pragma unroll
      for (int c = 0; c < NB; ++c) {
        int j = c * 256 + tid, r = j >> 3, c8 = j & 7;
        gload16(BT + (size_t)(col0 + r) * K + kc + c8 * 8, Bs + (size_t)buf * BN * 64 + (c * 256 + w * 64) * 8);
      }
    };

    stage(0, 0);
    __syncthreads();
    const int NK = K / 64;
    for (int t = 0; t < NK; ++t) {
      int buf = t & 1;
      if (t + 1 < NK) stage(buf ^ 1, (t + 1) * 64);
#pragma unroll
      for (int kk = 0; kk < 2; ++kk) {
        short8 af[FM], bfm[FN];
#pragma unroll
        for (int f = 0; f < FM; ++f)
          af[f] = *(const short8*)(As + (size_t)buf * BM * 64 + (wr * FM * 16 + f * 16 + l15) * 64 + kk * 32 + lhi * 8);
#pragma unroll
        for (int f = 0; f < FN; ++f)
          bfm[f] = *(const short8*)(Bs + (size_t)buf * BN * 64 + (wc * FN * 16 + f * 16 + l15) * 64 + kk * 32 + lhi * 8);
#pragma unroll
        for (int fm = 0; fm < FM; ++fm)
#pragma unroll
          for (int fn = 0; fn < FN; ++fn)
            acc[fm][fn] = __builtin_amdgcn_mfma_f32_16x16x32_bf16(af[fm], bfm[fn], acc[fm][fn], 0, 0, 0);
      }
      __syncthreads();
    }

#pragma unroll
    for (int fm = 0; fm < FM; ++fm)
#pragma unroll
      for (int r = 0; r < 4; ++r) {
        int row = row0 + wr * FM * 16 + fm * 16 + lhi * 4 + r;
#pragma unroll
        for (int fn = 0; fn < FN; ++fn) {
          int col = col0 + wc * FN * 16 + fn * 16 + l15;
          float v = acc[fm][fn][r] + bias[col];
          if (EPI == 1) {
            v = v > 0.f ? v : 0.f;
            outb[(size_t)row * N + col] = tob(v);
          } else {
            float sres = xres[(size_t)row * N + col] + v;
            float y = gamma[col] * (sres * BN_SCALE) + beta[col];
            outf[(size_t)row * N + col] = y;
            outb[(size_t)row * N + col] = tob(y);
          }
        }
      }
  }
}

// ================= phase: final GEMM (LDS-free, direct W fragments) =================
__device__ void phase_fgemm(const Params& p, const bf16* flatb) {
  const int tid = threadIdx.x, lane = tid & 63, w = tid >> 6;
  const int l15 = lane & 15, lhi = lane >> 4;
  for (int u = blockIdx.x; u < 32 * FG_KS; u += gridDim.x) {
    const int chunk = u & 31, ks = u >> 5;
    const int c0 = (chunk < 31) ? chunk * 256 : (VV - 256);  // overlap dup-writes: benign
    const int k0 = ks * FG_KCH;
    const int wcb = c0 + w * 64;
    f32x4 acc[2][4] = {};
#pragma unroll 2
    for (int it = 0; it < FG_KCH / 32; ++it) {
      const int kb = k0 + it * 32 + lhi * 8;
      float wv[4][8];
#pragma unroll
      for (int ct = 0; ct < 4; ++ct)
#pragma unroll
        for (int j = 0; j < 8; ++j)
          wv[ct][j] = p.out_w[(size_t)(kb + j) * VV + wcb + ct * 16 + l15];
      short8 af[2];
#pragma unroll
      for (int mt = 0; mt < 2; ++mt)
        af[mt] = *(const short8*)(flatb + (size_t)(mt * 16 + l15) * (SS * DD) + k0 + it * 32 + lhi * 8);
#pragma unroll
      for (int ct = 0; ct < 4; ++ct) {
        short8 bfr;
#pragma unroll
        for (int j = 0; j < 8; ++j) { bf16 hb = tob(wv[ct][j]); bfr[j] = *reinterpret_cast<const short*>(&hb); }
#pragma unroll
        for (int mt = 0; mt < 2; ++mt)
          acc[mt][ct] = __builtin_amdgcn_mfma_f32_16x16x32_bf16(af[mt], bfr, acc[mt][ct], 0, 0, 0);
      }
    }
    float* pp = p.fpart + (size_t)ks * 32 * VV;
#pragma unroll
    for (int mt = 0; mt < 2; ++mt)
#pragma unroll
      for (int ct = 0; ct < 4; ++ct)
#pragma unroll
        for (int r = 0; r < 4; ++r)
          pp[(size_t)(mt * 16 + lhi * 4 + r) * VV + c0 + w * 64 + ct * 16 + l15] = acc[mt][ct][r];
  }
}

__device__ void phase_freduce(const Params& p) {
  for (int i = blockIdx.x * 256 + threadIdx.x; i < 32 * VV; i += gridDim.x * 256) {
    int b = i / VV, c = i % VV;
    float s = p.out_b[c];
#pragma unroll
    for (int ks = 0; ks < FG_KS; ++ks)
      s += p.fpart[((size_t)ks * 32 + b) * VV + c];
    p.out[i] = s;
  }
}

// ================= cooperative mega kernel =================
__global__ __launch_bounds__(256, 2) void mega(Params p) {
  cg::grid_group grid = cg::this_grid();
  __shared__ __align__(16) char smem[MEGA_SMEM];

  phase_prep(p, smem);
  __threadfence(); grid.sync();
  phase_cakv(p, smem);
  __threadfence(); grid.sync();

  float* xc = p.x0; float* xa = p.x1;
  bf16* xbc = p.xb0; bf16* xba = p.xb1;
  for (int i = 0; i < LL; ++i) {
    phase_attn<true>(p, smem, i, xbc, xc, xa, xba);
    __threadfence(); grid.sync();
    phase_attn<false>(p, smem, i, xba, xa, xc, xbc);
    __threadfence(); grid.sync();
    phase_mm<128, 64, 2, 2, 1>(smem, xbc, p.w1T + (size_t)i * DD * FF, DD, FF,
                               p.f_b1 + (size_t)i * FF, p.h, nullptr, nullptr, nullptr, nullptr, 16, 32);
    __threadfence(); grid.sync();
    phase_mm<64, 64, 2, 2, 2>(smem, p.h, p.w2T + (size_t)i * DD * FF, FF, DD,
                              p.f_b2 + (size_t)i * DD, xba, xa, xc,
                              p.bn_g + (size_t)(i * 3 + 2) * DD, p.bn_b + (size_t)(i * 3 + 2) * DD, 32, 8);
    __threadfence(); grid.sync();
    { float* t = xc; xc = xa; xa = t; }
    { bf16* t = xbc; xbc = xba; xba = t; }
  }

  phase_fgemm(p, xbc);
  __threadfence(); grid.sync();
  phase_freduce(p);
}

// ================= fallback wrappers =================
__global__ __launch_bounds__(256) void k_prep(Params p) {
  __shared__ __align__(16) char s[4224]; phase_prep(p, s);
}
__global__ __launch_bounds__(256) void k_cakv(Params p) {
  __shared__ __align__(16) char s[18432]; phase_cakv(p, s);
}
template <bool C>
__global__ __launch_bounds__(256) void k_attn(Params p, int i, const bf16* qin,
                                              const float* xres, float* xout, bf16* xbout) {
  __shared__ __align__(16) char s[ATTN_SMEM]; phase_attn<C>(p, s, i, qin, xres, xout, xbout);
}
template <int BM, int BN, int WM, int WN, int EPI>
__global__ __launch_bounds__(256) void k_mm(const bf16* A, const bf16* BT, int K, int N,
                                            const float* bias, bf16* outb, float* outf,
                                            const float* xres, const float* gamma, const float* beta,
                                            int MT, int NT) {
  __shared__ __align__(16) char s[(2 * BM * 64 + 2 * BN * 64) * 2];
  phase_mm<BM, BN, WM, WN, EPI>(s, A, BT, K, N, bias, outb, outf, xres, gamma, beta, MT, NT);
}
__global__ __launch_bounds__(256) void k_fgemm(Params p, const bf16* flatb) { phase_fgemm(p, flatb); }
__global__ __launch_bounds__(256) void k_freduce(Params p) { phase_freduce(p); }

// ================= launch =================
extern "C" void kernel_launch(void* const* d_in, const int* in_sizes, int n_in,
                              void* d_out, int out_size, void* d_ws, size_t ws_size,
                              hipStream_t stream) {
  Params p;
  p.seq   = (const int*)  d_in[0];
  p.enc   = (const float*)d_in[1];
  p.pes   = (const float*)d_in[2];
  p.emb   = (const float*)d_in[3];
  p.sa_wq = (const float*)d_in[4];  p.sa_bq = (const float*)d_in[5];
  p.sa_wk = (const float*)d_in[6];  p.sa_bk = (const float*)d_in[7];
  p.sa_wv = (const float*)d_in[8];  p.sa_bv = (const float*)d_in[9];
  p.sa_wo = (const float*)d_in[10]; p.sa_bo = (const float*)d_in[11];
  p.ca_wq = (const float*)d_in[12]; p.ca_bq = (const float*)d_in[13];
  p.ca_wk = (const float*)d_in[14]; p.ca_bk = (const float*)d_in[15];
  p.ca_wv = (const float*)d_in[16]; p.ca_bv = (const float*)d_in[17];
  p.ca_wo = (const float*)d_in[18]; p.ca_bo = (const float*)d_in[19];
  p.f_w1  = (const float*)d_in[20]; p.f_b1  = (const float*)d_in[21];
  p.f_w2  = (const float*)d_in[22]; p.f_b2  = (const float*)d_in[23];
  p.bn_g  = (const float*)d_in[24]; p.bn_b  = (const float*)d_in[25];
  p.out_w = (const float*)d_in[26]; p.out_b = (const float*)d_in[27];
  p.out = (float*)d_out;

  char* wp = (char*)d_ws;
  size_t off = 0;
  auto alloc = [&](size_t bytes) { void* q = wp + off; off += (bytes + 255) & ~(size_t)255; return q; };
  p.x0  = (float*)alloc((size_t)BS * DD * 4);
  p.x1  = (float*)alloc((size_t)BS * DD * 4);
  p.xb0 = (bf16*)alloc((size_t)BS * DD * 2);
  p.xb1 = (bf16*)alloc((size_t)BS * DD * 2);
  p.h   = (bf16*)alloc((size_t)BS * FF * 2);
  p.w1T = (bf16*)alloc((size_t)LL * DD * FF * 2);
  p.w2T = (bf16*)alloc((size_t)LL * DD * FF * 2);
  p.qkvTs = (bf16*)alloc((size_t)LL * 192 * DD * 2);
  p.qkvTc = (bf16*)alloc((size_t)LL * 192 * DD * 2);
  p.woTs  = (bf16*)alloc((size_t)LL * DD * DKK * 2);
  p.woTc  = (bf16*)alloc((size_t)LL * DD * DKK * 2);
  p.encb  = (bf16*)alloc((size_t)32 * SS * DD * 2);
  p.kca   = (bf16*)alloc((size_t)LL * BS * DKK * 2);
  p.vtca  = (bf16*)alloc((size_t)LL * BS * DKK * 2);
  p.fpart = (float*)alloc((size_t)FG_KS * 32 * VV * 4);

  void* kargs[] = {(void*)&p};
  hipError_t rc = hipLaunchCooperativeKernel((const void*)mega, dim3(256), dim3(256), kargs, 0, stream);
  if (rc != hipSuccess) {
    (void)hipGetLastError();   // clear sticky error, fall back to discrete launches
    k_prep<<<512, 256, 0, stream>>>(p);
    k_cakv<<<128, 256, 0, stream>>>(p);
    float* xc = p.x0; float* xa = p.x1;
    bf16* xbc = p.xb0; bf16* xba = p.xb1;
    for (int i = 0; i < LL; ++i) {
      k_attn<true><<<256, 256, 0, stream>>>(p, i, xbc, xc, xa, xba);
      k_attn<false><<<256, 256, 0, stream>>>(p, i, xba, xa, xc, xbc);
      k_mm<128, 64, 2, 2, 1><<<512, 256, 0, stream>>>(
          xbc, p.w1T + (size_t)i * DD * FF, DD, FF, p.f_b1 + (size_t)i * FF,
          p.h, nullptr, nullptr, nullptr, nullptr, 16, 32);
      k_mm<64, 64, 2, 2, 2><<<256, 256, 0, stream>>>(
          p.h, p.w2T + (size_t)i * DD * FF, FF, DD, p.f_b2 + (size_t)i * DD,
          xba, xa, xc, p.bn_g + (size_t)(i * 3 + 2) * DD, p.bn_b + (size_t)(i * 3 + 2) * DD, 32, 8);
      { float* t = xc; xc = xa; xa = t; }
      { bf16* t = xbc; xbc = xba; xba = t; }
    }
    k_fgemm<<<256, 256, 0, stream>>>(p, xbc);
    k_freduce<<<256, 256, 0, stream>>>(p);
  }
}

// Round 8
// 590.948 us; speedup vs baseline: 2.7856x; 2.7856x over previous
//
#include <hip/hip_runtime.h>
#include <hip/hip_bf16.h>
#include <cstddef>

#define DD 512
#define DKK 64
#define SS 64
#define BS 2048
#define FF 2048
#define VV 8000
#define LL 4
#define BN_SCALE 0.9995003746f
#define FG_KS 16
#define FG_KCH 2048

typedef __attribute__((ext_vector_type(8))) short short8;
typedef __attribute__((ext_vector_type(4))) float f32x4;
typedef __hip_bfloat16 bf16;

__device__ __forceinline__ void gload16(const void* g, void* l) {
  __builtin_amdgcn_global_load_lds((const __attribute__((address_space(1))) void*)g,
                                   (__attribute__((address_space(3))) void*)l, 16, 0, 0);
}
__device__ __forceinline__ bf16 tob(float v) { return __float2bfloat16(v); }

// ---------------------------------------------------------------- merged preprocessing
// [0,4096) w1T ; [4096,8192) w2T ; [8192,8960) qkvT ; [8960,9216) woT ;
// [9216,13312) enc->bf16 ; [13312,17408) embed ; 17408: zero tickets
__global__ __launch_bounds__(256) void prep_kernel(
    const float* __restrict__ f_w1, const float* __restrict__ f_w2,
    const float* __restrict__ sa_wq, const float* __restrict__ sa_wk, const float* __restrict__ sa_wv,
    const float* __restrict__ ca_wq, const float* __restrict__ ca_wk, const float* __restrict__ ca_wv,
    const float* __restrict__ sa_wo, const float* __restrict__ ca_wo,
    const float* __restrict__ enc, const int* __restrict__ seq,
    const float* __restrict__ emb, const float* __restrict__ pes,
    bf16* __restrict__ w1T, bf16* __restrict__ w2T,
    bf16* __restrict__ qkvTs, bf16* __restrict__ qkvTc,
    bf16* __restrict__ woTs, bf16* __restrict__ woTc,
    bf16* __restrict__ encb, float* __restrict__ x, bf16* __restrict__ xb,
    int* __restrict__ ticket) {
  __shared__ float t[32][33];
  const int bid = blockIdx.x;
  const int tid = threadIdx.x;
  const int tx = tid & 31, ty = tid >> 5;

  auto tr = [&](const float* src, int srcld, bf16* dst, int dstld, int n0, int k0) {
#pragma unroll
    for (int p = 0; p < 4; ++p)
      t[ty + p * 8][tx] = src[(size_t)(k0 + ty + p * 8) * srcld + n0 + tx];
    __syncthreads();
#pragma unroll
    for (int p = 0; p < 4; ++p)
      dst[(size_t)(n0 + ty + p * 8) * dstld + k0 + tx] = tob(t[tx][ty + p * 8]);
  };

  if (bid < 4096) {
    int z = bid >> 10, rem = bid & 1023, kb = rem >> 6, nb = rem & 63;
    tr(f_w1 + (size_t)z * DD * FF, FF, w1T + (size_t)z * FF * DD, DD, nb * 32, kb * 32);
  } else if (bid < 8192) {
    int q = bid - 4096;
    int z = q >> 10, rem = q & 1023, nb = rem & 15, kb = rem >> 4;
    tr(f_w2 + (size_t)z * FF * DD, DD, w2T + (size_t)z * DD * FF, FF, nb * 32, kb * 32);
  } else if (bid < 8960) {
    int q = bid - 8192;
    int z = q >> 5, rem = q & 31, nb = rem & 1, kb = rem >> 1;
    int side = z / 12, r2 = z % 12, i = r2 / 3, which = r2 % 3;
    int sel = side * 3 + which;
    const float* base = sel == 0 ? sa_wq : sel == 1 ? sa_wk : sel == 2 ? sa_wv
                      : sel == 3 ? ca_wq : sel == 4 ? ca_wk : ca_wv;
    bf16* dst = (side ? qkvTc : qkvTs) + (size_t)i * 192 * DD + (size_t)which * 64 * DD;
    tr(base + (size_t)i * DD * DKK, DKK, dst, DD, nb * 32, kb * 32);
  } else if (bid < 9216) {
    int q = bid - 8960;
    int z = q >> 5, rem = q & 31, nb = rem >> 1, kb = rem & 1;
    int side = z / LL, i = z % LL;
    const float* base = (side ? ca_wo : sa_wo) + (size_t)i * DKK * DD;
    bf16* dst = (side ? woTc : woTs) + (size_t)i * DD * DKK;
    tr(base, DD, dst, DKK, nb * 32, kb * 32);
  } else if (bid < 13312) {
    int i = (bid - 9216) * 256 + tid;
    encb[i] = tob(enc[i]);
  } else if (bid < 17408) {
    int idx = (bid - 13312) * 256 + tid;
    int bs = idx / DD, d = idx % DD, s = bs % SS;
    float v = emb[(size_t)seq[bs] * DD + d] + pes[s * DD + d];
    x[idx]  = v;
    xb[idx] = tob(v);
  } else {
    if (tid < 32) ticket[tid] = 0;
  }
}

// ---------------------------------------------------------------- CA K/V precompute (all layers)
__global__ __launch_bounds__(256) void cakv_kernel(
    const bf16* __restrict__ qkvTc, const bf16* __restrict__ encb,
    const float* __restrict__ ca_bk, const float* __restrict__ ca_bv,
    bf16* __restrict__ kca, bf16* __restrict__ vtca) {
  __shared__ bf16 Ws[128][72];
  const int tid = threadIdx.x, w = tid >> 6, lane = tid & 63;
  const int l15 = lane & 15, lhi = lane >> 4;
  const int b = blockIdx.x & 31, i = blockIdx.x >> 5;
  const bf16* wT = qkvTc + (size_t)i * 192 * DD + (size_t)64 * DD;
  f32x4 acc[8] = {};
  for (int kc = 0; kc < DD; kc += 64) {
    __syncthreads();
#pragma unroll
    for (int v = 0; v < 4; ++v) {
      int idx = v * 256 + tid, row = idx >> 3, c8 = idx & 7;
      *(short8*)&Ws[row][c8 * 8] = *(const short8*)(wT + (size_t)row * DD + kc + c8 * 8);
    }
    __syncthreads();
#pragma unroll
    for (int kk = 0; kk < 2; ++kk) {
      short8 ae = *(const short8*)(encb + (size_t)(b * 64 + w * 16 + l15) * DD + kc + kk * 32 + lhi * 8);
#pragma unroll
      for (int f = 0; f < 8; ++f) {
        short8 bfr = *(const short8*)&Ws[f * 16 + l15][kk * 32 + lhi * 8];
        acc[f] = __builtin_amdgcn_mfma_f32_16x16x32_bf16(ae, bfr, acc[f], 0, 0, 0);
      }
    }
  }
  const float* bk = ca_bk + i * DKK;
  const float* bv = ca_bv + i * DKK;
#pragma unroll
  for (int f = 0; f < 8; ++f) {
    int c = f * 16 + l15;
#pragma unroll
    for (int r = 0; r < 4; ++r) {
      int row = w * 16 + lhi * 4 + r;
      if (f < 4)
        kca[((size_t)i * BS + b * 64 + row) * DKK + c] = tob(acc[f][r] + bk[c]);
      else {
        int d = c - 64;
        vtca[(((size_t)i * 32 + b) * DKK + d) * 64 + row] = tob(acc[f][r] + bv[d]);
      }
    }
  }
}

// ---------------------------------------------------------------- self-attention (round-5 proven)
__global__ __launch_bounds__(256) void fused_attn_sa(
    const bf16* __restrict__ qin, const bf16* __restrict__ qkvT,
    const float* __restrict__ bq, const float* __restrict__ bk, const float* __restrict__ bv,
    const bf16* __restrict__ woT, const float* __restrict__ bo,
    const float* __restrict__ xres,
    const float* __restrict__ gamma, const float* __restrict__ beta,
    float* __restrict__ xout, bf16* __restrict__ xbout) {
  __shared__ bf16 Ws[192][72];
  __shared__ bf16 Qb[64][72], Kb[64][72], Vt[64][72], Pb[64][72], Hb[64][72];
  const int tid = threadIdx.x, w = tid >> 6, lane = tid & 63;
  const int l15 = lane & 15, lhi = lane >> 4;
  const int b = blockIdx.y, col0 = blockIdx.x * 128;
  const size_t abase = (size_t)(b * SS) * DD;

  f32x4 acc[12] = {};
  for (int kc = 0; kc < DD; kc += 64) {
    __syncthreads();
#pragma unroll
    for (int u = 0; u < 6; ++u) {
      int idx = u * 256 + tid, row = idx >> 3, c8 = idx & 7;
      *(short8*)&Ws[row][c8 * 8] = *(const short8*)(qkvT + (size_t)row * DD + kc + c8 * 8);
    }
    __syncthreads();
#pragma unroll
    for (int kk = 0; kk < 2; ++kk) {
      short8 aq = *(const short8*)(qin + abase + (size_t)(w * 16 + l15) * DD + kc + kk * 32 + lhi * 8);
#pragma unroll
      for (int f = 0; f < 12; ++f) {
        short8 bfr = *(const short8*)&Ws[f * 16 + l15][kk * 32 + lhi * 8];
        acc[f] = __builtin_amdgcn_mfma_f32_16x16x32_bf16(aq, bfr, acc[f], 0, 0, 0);
      }
    }
  }
#pragma unroll
  for (int f = 0; f < 12; ++f) {
    int c = (f & 3) * 16 + l15;
#pragma unroll
    for (int r = 0; r < 4; ++r) {
      int row = w * 16 + lhi * 4 + r;
      if (f < 4)      Qb[row][c] = tob((acc[f][r] + bq[c]) * 0.125f);
      else if (f < 8) Kb[row][c] = tob(acc[f][r] + bk[c]);
      else            Vt[c][row] = tob(acc[f][r] + bv[c]);
    }
  }
  __syncthreads();

  f32x4 sacc[4] = {};
#pragma unroll
  for (int kk = 0; kk < 2; ++kk) {
    short8 aq = *(const short8*)&Qb[w * 16 + l15][kk * 32 + lhi * 8];
#pragma unroll
    for (int f = 0; f < 4; ++f) {
      short8 bfr = *(const short8*)&Kb[f * 16 + l15][kk * 32 + lhi * 8];
      sacc[f] = __builtin_amdgcn_mfma_f32_16x16x32_bf16(aq, bfr, sacc[f], 0, 0, 0);
    }
  }
#pragma unroll
  for (int r = 0; r < 4; ++r) {
    int qr = w * 16 + lhi * 4 + r;
    float sv[4], m = -3.0e38f;
#pragma unroll
    for (int f = 0; f < 4; ++f) {
      int kt = f * 16 + l15;
      bool valid = kt < qr;
      sv[f] = valid ? sacc[f][r] : -3.0e38f;
      m = fmaxf(m, sv[f]);
    }
#pragma unroll
    for (int off = 1; off < 16; off <<= 1) m = fmaxf(m, __shfl_xor(m, off));
    float pv[4], sum = 0.f;
#pragma unroll
    for (int f = 0; f < 4; ++f) {
      pv[f] = (sv[f] > -1.0e38f) ? __expf(sv[f] - m) : 0.f;
      sum += pv[f];
    }
#pragma unroll
    for (int off = 1; off < 16; off <<= 1) sum += __shfl_xor(sum, off);
    float rs = sum > 0.f ? 1.f / sum : 0.f;
#pragma unroll
    for (int f = 0; f < 4; ++f)
      Pb[qr][f * 16 + l15] = tob(pv[f] * rs);
  }
  __syncthreads();

  f32x4 hacc[4] = {};
#pragma unroll
  for (int kk = 0; kk < 2; ++kk) {
    short8 ap = *(const short8*)&Pb[w * 16 + l15][kk * 32 + lhi * 8];
#pragma unroll
    for (int f = 0; f < 4; ++f) {
      short8 bfr = *(const short8*)&Vt[f * 16 + l15][kk * 32 + lhi * 8];
      hacc[f] = __builtin_amdgcn_mfma_f32_16x16x32_bf16(ap, bfr, hacc[f], 0, 0, 0);
    }
  }
#pragma unroll
  for (int f = 0; f < 4; ++f)
#pragma unroll
    for (int r = 0; r < 4; ++r)
      Hb[w * 16 + lhi * 4 + r][f * 16 + l15] = tob(hacc[f][r]);
  __syncthreads();

  f32x4 oacc[8] = {};
#pragma unroll
  for (int kk = 0; kk < 2; ++kk) {
    short8 ah = *(const short8*)&Hb[w * 16 + l15][kk * 32 + lhi * 8];
#pragma unroll
    for (int f = 0; f < 8; ++f) {
      short8 bfr = *(const short8*)(woT + (size_t)(col0 + f * 16 + l15) * DKK + kk * 32 + lhi * 8);
      oacc[f] = __builtin_amdgcn_mfma_f32_16x16x32_bf16(ah, bfr, oacc[f], 0, 0, 0);
    }
  }
#pragma unroll
  for (int f = 0; f < 8; ++f) {
    int c = col0 + f * 16 + l15;
    float g = gamma[c], be = beta[c], bb = bo[c];
#pragma unroll
    for (int r = 0; r < 4; ++r) {
      int row = b * SS + w * 16 + lhi * 4 + r;
      float v = oacc[f][r] + bb;
      float res = xres[(size_t)row * DD + c] + v;
      float y = g * (res * BN_SCALE) + be;
      xout[(size_t)row * DD + c]  = y;
      xbout[(size_t)row * DD + c] = tob(y);
    }
  }
}

// ---------------------------------------------------------------- cross-attention (hoisted K/V)
__global__ __launch_bounds__(256) void fused_attn_ca(
    const bf16* __restrict__ qin, const bf16* __restrict__ kca, const bf16* __restrict__ vtca,
    const bf16* __restrict__ qT, const float* __restrict__ bq,
    const bf16* __restrict__ woT, const float* __restrict__ bo,
    const float* __restrict__ xres,
    const float* __restrict__ gamma, const float* __restrict__ beta,
    float* __restrict__ xout, bf16* __restrict__ xbout) {
  __shared__ bf16 Ws[64][72];
  __shared__ bf16 Qb[64][72], Kb[64][72], Vt[64][72], Pb[64][72], Hb[64][72];
  const int tid = threadIdx.x, w = tid >> 6, lane = tid & 63;
  const int l15 = lane & 15, lhi = lane >> 4;
  const int b = blockIdx.y, col0 = blockIdx.x * 128;
  const size_t abase = (size_t)(b * SS) * DD;

  // stage precomputed K,V
#pragma unroll
  for (int v = 0; v < 2; ++v) {
    int idx = v * 256 + tid, r = idx >> 3, c8 = idx & 7;
    *(short8*)&Kb[r][c8 * 8] = *(const short8*)(kca + ((size_t)b * 64 + r) * DKK + c8 * 8);
    *(short8*)&Vt[r][c8 * 8] = *(const short8*)(vtca + ((size_t)b * DKK + r) * 64 + c8 * 8);
  }

  f32x4 acc[4] = {};
  for (int kc = 0; kc < DD; kc += 64) {
    __syncthreads();
#pragma unroll
    for (int v = 0; v < 2; ++v) {
      int idx = v * 256 + tid, row = idx >> 3, c8 = idx & 7;
      *(short8*)&Ws[row][c8 * 8] = *(const short8*)(qT + (size_t)row * DD + kc + c8 * 8);
    }
    __syncthreads();
#pragma unroll
    for (int kk = 0; kk < 2; ++kk) {
      short8 aq = *(const short8*)(qin + abase + (size_t)(w * 16 + l15) * DD + kc + kk * 32 + lhi * 8);
#pragma unroll
      for (int f = 0; f < 4; ++f) {
        short8 bfr = *(const short8*)&Ws[f * 16 + l15][kk * 32 + lhi * 8];
        acc[f] = __builtin_amdgcn_mfma_f32_16x16x32_bf16(aq, bfr, acc[f], 0, 0, 0);
      }
    }
  }
#pragma unroll
  for (int f = 0; f < 4; ++f) {
    int c = f * 16 + l15;
#pragma unroll
    for (int r = 0; r < 4; ++r)
      Qb[w * 16 + lhi * 4 + r][c] = tob((acc[f][r] + bq[c]) * 0.125f);
  }
  __syncthreads();

  f32x4 sacc[4] = {};
#pragma unroll
  for (int kk = 0; kk < 2; ++kk) {
    short8 aq = *(const short8*)&Qb[w * 16 + l15][kk * 32 + lhi * 8];
#pragma unroll
    for (int f = 0; f < 4; ++f) {
      short8 bfr = *(const short8*)&Kb[f * 16 + l15][kk * 32 + lhi * 8];
      sacc[f] = __builtin_amdgcn_mfma_f32_16x16x32_bf16(aq, bfr, sacc[f], 0, 0, 0);
    }
  }
#pragma unroll
  for (int r = 0; r < 4; ++r) {
    int qr = w * 16 + lhi * 4 + r;
    float sv[4], m = -3.0e38f;
#pragma unroll
    for (int f = 0; f < 4; ++f) { sv[f] = sacc[f][r]; m = fmaxf(m, sv[f]); }
#pragma unroll
    for (int off = 1; off < 16; off <<= 1) m = fmaxf(m, __shfl_xor(m, off));
    float pv[4], sum = 0.f;
#pragma unroll
    for (int f = 0; f < 4; ++f) { pv[f] = __expf(sv[f] - m); sum += pv[f]; }
#pragma unroll
    for (int off = 1; off < 16; off <<= 1) sum += __shfl_xor(sum, off);
    float rs = 1.f / sum;
#pragma unroll
    for (int f = 0; f < 4; ++f)
      Pb[qr][f * 16 + l15] = tob(pv[f] * rs);
  }
  __syncthreads();

  f32x4 hacc[4] = {};
#pragma unroll
  for (int kk = 0; kk < 2; ++kk) {
    short8 ap = *(const short8*)&Pb[w * 16 + l15][kk * 32 + lhi * 8];
#pragma unroll
    for (int f = 0; f < 4; ++f) {
      short8 bfr = *(const short8*)&Vt[f * 16 + l15][kk * 32 + lhi * 8];
      hacc[f] = __builtin_amdgcn_mfma_f32_16x16x32_bf16(ap, bfr, hacc[f], 0, 0, 0);
    }
  }
#pragma unroll
  for (int f = 0; f < 4; ++f)
#pragma unroll
    for (int r = 0; r < 4; ++r)
      Hb[w * 16 + lhi * 4 + r][f * 16 + l15] = tob(hacc[f][r]);
  __syncthreads();

  f32x4 oacc[8] = {};
#pragma unroll
  for (int kk = 0; kk < 2; ++kk) {
    short8 ah = *(const short8*)&Hb[w * 16 + l15][kk * 32 + lhi * 8];
#pragma unroll
    for (int f = 0; f < 8; ++f) {
      short8 bfr = *(const short8*)(woT + (size_t)(col0 + f * 16 + l15) * DKK + kk * 32 + lhi * 8);
      oacc[f] = __builtin_amdgcn_mfma_f32_16x16x32_bf16(ah, bfr, oacc[f], 0, 0, 0);
    }
  }
#pragma unroll
  for (int f = 0; f < 8; ++f) {
    int c = col0 + f * 16 + l15;
    float g = gamma[c], be = beta[c], bb = bo[c];
#pragma unroll
    for (int r = 0; r < 4; ++r) {
      int row = b * SS + w * 16 + lhi * 4 + r;
      float v = oacc[f][r] + bb;
      float res = xres[(size_t)row * DD + c] + v;
      float y = g * (res * BN_SCALE) + be;
      xout[(size_t)row * DD + c]  = y;
      xbout[(size_t)row * DD + c] = tob(y);
    }
  }
}

// ---------------------------------------------------------------- bf16 MFMA GEMM (gload_lds + dbuf)
template <int BM, int BN, int WM, int WN, int EPI>
__global__ __launch_bounds__(256) void mm_bf16(
    const bf16* __restrict__ A, const bf16* __restrict__ BT,
    int K, int N, const float* __restrict__ bias,
    bf16* __restrict__ outb, float* __restrict__ outf,
    const float* __restrict__ xres,
    const float* __restrict__ gamma, const float* __restrict__ beta) {
  constexpr int NA = BM * 64 / 8 / 256;
  constexpr int NB = BN * 64 / 8 / 256;
  constexpr int FM = BM / (WM * 16), FN = BN / (WN * 16);
  __shared__ __align__(16) bf16 As[2][BM * 64];
  __shared__ __align__(16) bf16 Bs[2][BN * 64];
  const int tid = threadIdx.x, lane = tid & 63, w = tid >> 6;
  const int wr = w / WN, wc = w % WN;
  const int l15 = lane & 15, lhi = lane >> 4;
  const int row0 = blockIdx.x * BM, col0 = blockIdx.y * BN;
  f32x4 acc[FM][FN] = {};

  auto stage = [&](int buf, int kc) {
#pragma unroll
    for (int c = 0; c < NA; ++c) {
      int j = c * 256 + tid, r = j >> 3, c8 = j & 7;
      gload16(A + (size_t)(row0 + r) * K + kc + c8 * 8, &As[buf][(c * 256 + w * 64) * 8]);
    }
#pragma unroll
    for (int c = 0; c < NB; ++c) {
      int j = c * 256 + tid, r = j >> 3, c8 = j & 7;
      gload16(BT + (size_t)(col0 + r) * K + kc + c8 * 8, &Bs[buf][(c * 256 + w * 64) * 8]);
    }
  };

  stage(0, 0);
  __syncthreads();
  const int NK = K / 64;
  for (int t = 0; t < NK; ++t) {
    int buf = t & 1;
    if (t + 1 < NK) stage(buf ^ 1, (t + 1) * 64);
#pragma unroll
    for (int kk = 0; kk < 2; ++kk) {
      short8 af[FM], bfm[FN];
#pragma unroll
      for (int f = 0; f < FM; ++f)
        af[f] = *(const short8*)(&As[buf][(wr * FM * 16 + f * 16 + l15) * 64 + kk * 32 + lhi * 8]);
#pragma unroll
      for (int f = 0; f < FN; ++f)
        bfm[f] = *(const short8*)(&Bs[buf][(wc * FN * 16 + f * 16 + l15) * 64 + kk * 32 + lhi * 8]);
#pragma unroll
      for (int fm = 0; fm < FM; ++fm)
#pragma unroll
        for (int fn = 0; fn < FN; ++fn)
          acc[fm][fn] = __builtin_amdgcn_mfma_f32_16x16x32_bf16(af[fm], bfm[fn], acc[fm][fn], 0, 0, 0);
    }
    __syncthreads();
  }

#pragma unroll
  for (int fm = 0; fm < FM; ++fm)
#pragma unroll
    for (int r = 0; r < 4; ++r) {
      int row = row0 + wr * FM * 16 + fm * 16 + lhi * 4 + r;
#pragma unroll
      for (int fn = 0; fn < FN; ++fn) {
        int col = col0 + wc * FN * 16 + fn * 16 + l15;
        float v = acc[fm][fn][r] + bias[col];
        if (EPI == 1) {
          v = v > 0.f ? v : 0.f;
          outb[(size_t)row * N + col] = tob(v);
        } else {
          float sres = xres[(size_t)row * N + col] + v;
          float y = gamma[col] * (sres * BN_SCALE) + beta[col];
          outf[(size_t)row * N + col] = y;
          outb[(size_t)row * N + col] = tob(y);
        }
      }
    }
}

// ---------------------------------------------------------------- final GEMM: MFMA + fused last-block reduce
__global__ __launch_bounds__(256) void fgemm_mfma(
    const bf16* __restrict__ flatb, const float* __restrict__ wout,
    const float* __restrict__ out_b, float* __restrict__ fpart,
    int* __restrict__ ticket, float* __restrict__ out) {
  __shared__ float Ws[2][32][257];          // pad 257: 2-way bank aliasing (free)
  __shared__ int lastf;
  const int tid = threadIdx.x, lane = tid & 63, w = tid >> 6;
  const int l15 = lane & 15, lhi = lane >> 4;
  const int chunk = blockIdx.x, ks = blockIdx.y;
  const int c0 = (chunk < 31) ? chunk * 256 : (VV - 256);  // overlap dup-writes: benign
  const int k0 = ks * FG_KCH;
  f32x4 acc[2][4] = {};

  auto stageW = [&](int buf, int it) {
    const float* src = wout + (size_t)(k0 + it * 32) * VV + c0;
#pragma unroll
    for (int i2 = 0; i2 < 8; ++i2) {
      int row = i2 * 4 + w;
      gload16(src + (size_t)row * VV + lane * 4, &Ws[buf][row][0]);
    }
  };

  stageW(0, 0);
  __syncthreads();
  for (int it = 0; it < FG_KCH / 32; ++it) {
    int buf = it & 1;
    if (it + 1 < FG_KCH / 32) stageW(buf ^ 1, it + 1);
    short8 af[2];
#pragma unroll
    for (int mt = 0; mt < 2; ++mt)
      af[mt] = *(const short8*)(flatb + (size_t)(mt * 16 + l15) * (SS * DD) + k0 + it * 32 + lhi * 8);
#pragma unroll
    for (int ct = 0; ct < 4; ++ct) {
      int coll = w * 64 + ct * 16 + l15;
      short8 bfr;
#pragma unroll
      for (int j = 0; j < 8; ++j) {
        bf16 hb = tob(Ws[buf][lhi * 8 + j][coll]);
        bfr[j] = *reinterpret_cast<const short*>(&hb);
      }
#pragma unroll
      for (int mt = 0; mt < 2; ++mt)
        acc[mt][ct] = __builtin_amdgcn_mfma_f32_16x16x32_bf16(af[mt], bfr, acc[mt][ct], 0, 0, 0);
    }
    __syncthreads();
  }

  float* pp = fpart + (size_t)ks * 32 * VV;
#pragma unroll
  for (int mt = 0; mt < 2; ++mt)
#pragma unroll
    for (int ct = 0; ct < 4; ++ct)
#pragma unroll
      for (int r = 0; r < 4; ++r)
        pp[(size_t)(mt * 16 + lhi * 4 + r) * VV + c0 + w * 64 + ct * 16 + l15] = acc[mt][ct][r];

  // ---- fused reduction: last block per chunk sums partials + bias
  __threadfence();
  if (tid == 0) {
    int old = atomicAdd(&ticket[chunk], 1);
    lastf = (old == FG_KS - 1) ? 1 : 0;
  }
  __syncthreads();
  if (lastf) {
    __threadfence();
    for (int idx = tid; idx < 32 * 256; idx += 256) {
      int r = idx >> 8, c = idx & 255;
      int col = c0 + c;
      float s = out_b[col];
#pragma unroll
      for (int k2 = 0; k2 < FG_KS; ++k2)
        s += fpart[((size_t)k2 * 32 + r) * VV + col];
      out[(size_t)r * VV + col] = s;
    }
  }
}

// ---------------------------------------------------------------- launch
extern "C" void kernel_launch(void* const* d_in, const int* in_sizes, int n_in,
                              void* d_out, int out_size, void* d_ws, size_t ws_size,
                              hipStream_t stream) {
  const int*   seq   = (const int*)  d_in[0];
  const float* enc   = (const float*)d_in[1];
  const float* pes   = (const float*)d_in[2];
  const float* emb   = (const float*)d_in[3];
  const float* sa_wq = (const float*)d_in[4];
  const float* sa_bq = (const float*)d_in[5];
  const float* sa_wk = (const float*)d_in[6];
  const float* sa_bk = (const float*)d_in[7];
  const float* sa_wv = (const float*)d_in[8];
  const float* sa_bv = (const float*)d_in[9];
  const float* sa_wo = (const float*)d_in[10];
  const float* sa_bo = (const float*)d_in[11];
  const float* ca_wq = (const float*)d_in[12];
  const float* ca_bq = (const float*)d_in[13];
  const float* ca_wk = (const float*)d_in[14];
  const float* ca_bk = (const float*)d_in[15];
  const float* ca_wv = (const float*)d_in[16];
  const float* ca_bv = (const float*)d_in[17];
  const float* ca_wo = (const float*)d_in[18];
  const float* ca_bo = (const float*)d_in[19];
  const float* f_w1  = (const float*)d_in[20];
  const float* f_b1  = (const float*)d_in[21];
  const float* f_w2  = (const float*)d_in[22];
  const float* f_b2  = (const float*)d_in[23];
  const float* bn_g  = (const float*)d_in[24];
  const float* bn_b  = (const float*)d_in[25];
  const float* out_w = (const float*)d_in[26];
  const float* out_b = (const float*)d_in[27];
  float* out = (float*)d_out;

  char* wp = (char*)d_ws;
  size_t off = 0;
  auto alloc = [&](size_t bytes) { void* q = wp + off; off += (bytes + 255) & ~(size_t)255; return q; };
  float* x0 = (float*)alloc((size_t)BS * DD * 4);
  float* x1 = (float*)alloc((size_t)BS * DD * 4);
  bf16* xb0 = (bf16*)alloc((size_t)BS * DD * 2);
  bf16* xb1 = (bf16*)alloc((size_t)BS * DD * 2);
  bf16* h   = (bf16*)alloc((size_t)BS * FF * 2);
  bf16* w1T = (bf16*)alloc((size_t)LL * DD * FF * 2);
  bf16* w2T = (bf16*)alloc((size_t)LL * DD * FF * 2);
  bf16* qkvTs = (bf16*)alloc((size_t)LL * 192 * DD * 2);
  bf16* qkvTc = (bf16*)alloc((size_t)LL * 192 * DD * 2);
  bf16* woTs  = (bf16*)alloc((size_t)LL * DD * DKK * 2);
  bf16* woTc  = (bf16*)alloc((size_t)LL * DD * DKK * 2);
  bf16* encb  = (bf16*)alloc((size_t)32 * SS * DD * 2);
  bf16* kca   = (bf16*)alloc((size_t)LL * BS * DKK * 2);
  bf16* vtca  = (bf16*)alloc((size_t)LL * BS * DKK * 2);
  float* fpart = (float*)alloc((size_t)FG_KS * 32 * VV * 4);
  int* ticket  = (int*)alloc(32 * 4);

  prep_kernel<<<17409, 256, 0, stream>>>(
      f_w1, f_w2, sa_wq, sa_wk, sa_wv, ca_wq, ca_wk, ca_wv, sa_wo, ca_wo,
      enc, seq, emb, pes,
      w1T, w2T, qkvTs, qkvTc, woTs, woTc, encb, x0, xb0, ticket);
  cakv_kernel<<<128, 256, 0, stream>>>(qkvTc, encb, ca_bk, ca_bv, kca, vtca);

  float* xc = x0; float* xa = x1;
  bf16* xbc = xb0; bf16* xba = xb1;

  for (int i = 0; i < LL; ++i) {
    const float* g0  = bn_g + (size_t)(i * 3 + 0) * DD;
    const float* be0 = bn_b + (size_t)(i * 3 + 0) * DD;
    const float* g1  = bn_g + (size_t)(i * 3 + 1) * DD;
    const float* be1 = bn_b + (size_t)(i * 3 + 1) * DD;
    const float* g2  = bn_g + (size_t)(i * 3 + 2) * DD;
    const float* be2 = bn_b + (size_t)(i * 3 + 2) * DD;

    fused_attn_sa<<<dim3(4, 32), 256, 0, stream>>>(
        xbc, qkvTs + (size_t)i * 192 * DD,
        sa_bq + i * DKK, sa_bk + i * DKK, sa_bv + i * DKK,
        woTs + (size_t)i * DD * DKK, sa_bo + (size_t)i * DD,
        xc, g0, be0, xa, xba);
    fused_attn_ca<<<dim3(4, 32), 256, 0, stream>>>(
        xba, kca + (size_t)i * BS * DKK, vtca + (size_t)i * BS * DKK,
        qkvTc + (size_t)i * 192 * DD, ca_bq + i * DKK,
        woTc + (size_t)i * DD * DKK, ca_bo + (size_t)i * DD,
        xa, g1, be1, xc, xbc);
    mm_bf16<128, 128, 2, 2, 1><<<dim3(16, 16), 256, 0, stream>>>(
        xbc, w1T + (size_t)i * DD * FF, DD, FF, f_b1 + (size_t)i * FF,
        h, nullptr, nullptr, nullptr, nullptr);
    mm_bf16<64, 64, 2, 2, 2><<<dim3(32, 8), 256, 0, stream>>>(
        h, w2T + (size_t)i * DD * FF, FF, DD, f_b2 + (size_t)i * DD,
        xba, xa, xc, g2, be2);

    { float* t = xc; xc = xa; xa = t; }
    { bf16* t = xbc; xbc = xba; xba = t; }
  }

  fgemm_mfma<<<dim3(32, FG_KS), 256, 0, stream>>>(xbc, out_w, out_b, fpart, ticket, out);
}